// Round 2
// baseline (1586.695 us; speedup 1.0000x reference)
//
#include <hip/hip_runtime.h>
#include <math.h>

// (P, C, NX, NY, NT) = (2, 1, 128, 128, 8), T = 128
#define NP     2
#define NXD    128
#define NYD    128
#define NTD    8
#define PLANE  (NYD * NTD)        // 1024 sites per x-plane
#define NSITES (NP * NXD * PLANE) // 262144
#define NBLK   (NP * NXD)         // 256 blocks, one x-plane each
#define TSTEPS 128

#define AGENT __HIP_MEMORY_SCOPE_AGENT

__device__ __forceinline__ void gridbar(unsigned int* cnt, unsigned int target) {
    __syncthreads();  // drains each wave's vmcnt (all stores acked) before arrival
    if (threadIdx.x == 0) {
        __hip_atomic_fetch_add(cnt, 1u, __ATOMIC_RELEASE, AGENT);
        while (__hip_atomic_load(cnt, __ATOMIC_ACQUIRE, AGENT) < target) {
            __builtin_amdgcn_s_sleep(1);
        }
    }
    __syncthreads();
}

__global__ __launch_bounds__(1024, 4) void pdhg_persist(
    const float* __restrict__ x,
    const float* __restrict__ lam,
    const float* __restrict__ tau_p,
    const float* __restrict__ sigma_p,
    const float* __restrict__ theta_p,
    float* __restrict__ xbar_g,   // 2 * NSITES (ping-pong)
    float* __restrict__ q0_g,     // 2 * NSITES (ping-pong)
    unsigned int* __restrict__ cnt,
    float* __restrict__ out)
{
    __shared__ float xb_lds[2][PLANE];
    __shared__ float q1_lds[2][PLANE];
    __shared__ float q2_lds[2][PLANE];

    const int b   = blockIdx.x;        // plane = p*128 + ix
    const int tid = threadIdx.x;       // y*8 + t
    const int pp  = b >> 7;
    const int ix  = b & 127;
    const int idx = b * PLANE + tid;

    const int t = tid & 7;
    const int g_xp = ((pp << 7) + ((ix + 1) & 127)) * PLANE + tid;
    const int g_xm = ((pp << 7) + ((ix + 127) & 127)) * PLANE + tid;
    const int l_yp = (tid + 8) & (PLANE - 1);
    const int l_ym = (tid - 8) & (PLANE - 1);
    const int l_tp = (t == 7) ? tid - 7 : tid + 1;
    const int l_tm = (t == 0) ? tid + 7 : tid - 1;

    const float L = 3.605551275463989f;  // sqrt(13)
    const float s_sig = (1.f / (1.f + __expf(-sigma_p[0]))) / L;
    const float s_tau = (1.f / (1.f + __expf(-tau_p[0]))) / L;
    const float s_th  =  1.f / (1.f + __expf(-theta_p[0]));
    const float inv1s = 1.f / (1.f + s_sig);

    const float xn   = x[idx];
    const float lamc = lam[idx];
    const float lxm  = lam[g_xm];
    const float lym  = lam[b * PLANE + l_ym];
    const float ltm  = lam[b * PLANE + l_tm];

    // register-resident state for all 128 steps
    float x0v = xn, pv = xn, q0v = 0.f, q1v = 0.f, q2v = 0.f, xbv = xn;

    auto step_math = [&](float xbxp, float xbxm, float xbyp, float xbym,
                         float xbtp, float xbtm, float q0xm, float q1ym, float q2tm) {
        const float p_new = (pv + s_sig * (xbv - xn)) * inv1s;
        const float q0n = fmaxf(-lamc, fminf(lamc, q0v + s_sig * (xbxp - xbv)));
        const float q1n = fmaxf(-lamc, fminf(lamc, q1v + s_sig * (xbyp - xbv)));
        const float q2n = fmaxf(-lamc, fminf(lamc, q2v + s_sig * (xbtp - xbv)));
        // backward neighbors' new q (redundant compute -> single phase per step)
        const float q0nm = fmaxf(-lxm, fminf(lxm, q0xm + s_sig * (xbv - xbxm)));
        const float q1nm = fmaxf(-lym, fminf(lym, q1ym + s_sig * (xbv - xbym)));
        const float q2nm = fmaxf(-ltm, fminf(ltm, q2tm + s_sig * (xbv - xbtm)));
        const float div = (q0nm - q0n) + (q1nm - q1n) + (q2nm - q2n);
        const float x1 = x0v - s_tau * (p_new + div);
        const float xb_new = x1 + s_th * (x1 - x0v);
        pv = p_new; q0v = q0n; q1v = q1n; q2v = q2n;
        x0v = x1; xbv = xb_new;
    };

    // ---- step 0: xbar = x, q = 0, plain loads from input ----
    step_math(x[g_xp], x[g_xm],
              x[b * PLANE + l_yp], x[b * PLANE + l_ym],
              x[b * PLANE + l_tp], x[b * PLANE + l_tm],
              0.f, 0.f, 0.f);
    {
        const int w = 0;
        xb_lds[w][tid] = xbv; q1_lds[w][tid] = q1v; q2_lds[w][tid] = q2v;
        __hip_atomic_store(&xbar_g[w * NSITES + idx], xbv, __ATOMIC_RELAXED, AGENT);
        __hip_atomic_store(&q0_g[w * NSITES + idx],  q0v, __ATOMIC_RELAXED, AGENT);
        gridbar(cnt, NBLK);  // barrier after step 0
    }

    for (int s = 1; s < TSTEPS; ++s) {
        const int r = (s & 1) ^ 1;     // buffer published by step s-1
        const int w = s & 1;

        // cross-block (x +/- 1) via LLC-coherent loads
        const float xbxp = __hip_atomic_load(&xbar_g[r * NSITES + g_xp], __ATOMIC_RELAXED, AGENT);
        const float xbxm = __hip_atomic_load(&xbar_g[r * NSITES + g_xm], __ATOMIC_RELAXED, AGENT);
        const float q0xm = __hip_atomic_load(&q0_g[r * NSITES + g_xm],  __ATOMIC_RELAXED, AGENT);
        // in-plane neighbors via LDS
        const float xbyp = xb_lds[r][l_yp];
        const float xbym = xb_lds[r][l_ym];
        const float xbtp = xb_lds[r][l_tp];
        const float xbtm = xb_lds[r][l_tm];
        const float q1ym = q1_lds[r][l_ym];
        const float q2tm = q2_lds[r][l_tm];

        step_math(xbxp, xbxm, xbyp, xbym, xbtp, xbtm, q0xm, q1ym, q2tm);

        if (s < TSTEPS - 1) {
            xb_lds[w][tid] = xbv; q1_lds[w][tid] = q1v; q2_lds[w][tid] = q2v;
            __hip_atomic_store(&xbar_g[w * NSITES + idx], xbv, __ATOMIC_RELAXED, AGENT);
            __hip_atomic_store(&q0_g[w * NSITES + idx],  q0v, __ATOMIC_RELAXED, AGENT);
            gridbar(cnt, (unsigned)NBLK * (unsigned)(s + 1));
        }
    }

    out[idx] = x0v;   // x1 after step 127
}

extern "C" void kernel_launch(void* const* d_in, const int* in_sizes, int n_in,
                              void* d_out, int out_size, void* d_ws, size_t ws_size,
                              hipStream_t stream) {
    const float* x   = (const float*)d_in[0];
    const float* lam = (const float*)d_in[1];
    const float* tau = (const float*)d_in[2];
    const float* sig = (const float*)d_in[3];
    const float* th  = (const float*)d_in[4];
    float* out = (float*)d_out;

    float* ws = (float*)d_ws;
    float* xbar_g = ws;                               // 2*NSITES floats
    float* q0_g   = ws + 2 * (size_t)NSITES;          // 2*NSITES floats
    unsigned int* cnt = (unsigned int*)(ws + 4 * (size_t)NSITES);

    // ws is poisoned to 0xAA before every timed call: zero the barrier counter
    hipMemsetAsync(cnt, 0, sizeof(unsigned int), stream);

    void* args[] = {
        (void*)&x, (void*)&lam, (void*)&tau, (void*)&sig, (void*)&th,
        (void*)&xbar_g, (void*)&q0_g, (void*)&cnt, (void*)&out
    };
    hipLaunchCooperativeKernel((const void*)pdhg_persist,
                               dim3(NBLK), dim3(PLANE), args, 0, stream);
}

// Round 3
// 644.792 us; speedup vs baseline: 2.4608x; 2.4608x over previous
//
#include <hip/hip_runtime.h>
#include <math.h>

// (P, C, NX, NY, NT) = (2, 1, 128, 128, 8), T = 128
#define NP     2
#define NXD    128
#define NYD    128
#define NTD    8
#define PLANE  (NYD * NTD)        // 1024 sites per x-plane
#define NSITES (NP * NXD * PLANE) // 262144
#define NBLK   (NP * NXD)         // 256 blocks, one x-plane each
#define TSTEPS 128

#define AGENT __HIP_MEMORY_SCOPE_AGENT

// Two-level grid barrier. bar layout (units of unsigned):
//   leaf[g] at bar + g*16   (16 groups of 16 blocks, 64B apart)
//   root    at bar + 512
//   flag    at bar + 576
// All counters monotonic; flag==s once all 256 blocks arrived for step s.
__device__ __forceinline__ void gridbar(unsigned* __restrict__ bar, unsigned step) {
    __syncthreads();  // drains vmcnt: all waves' agent stores have reached LLC
    if (threadIdx.x == 0) {
        unsigned* leaf = bar + ((blockIdx.x >> 4) << 4);
        unsigned* root = bar + 512;
        unsigned* flag = bar + 576;
        const unsigned old = __hip_atomic_fetch_add(leaf, 1u, __ATOMIC_RELEASE, AGENT);
        if (old + 1u == 16u * step) {            // last of my 16-block group
            const unsigned r = __hip_atomic_fetch_add(root, 1u, __ATOMIC_RELAXED, AGENT);
            if (r + 1u == 16u * step) {          // last group overall
                __hip_atomic_store(flag, step, __ATOMIC_RELAXED, AGENT);
            }
        }
        while (__hip_atomic_load(flag, __ATOMIC_RELAXED, AGENT) < step) {
            __builtin_amdgcn_s_sleep(1);
        }
    }
    __syncthreads();
}

__global__ __launch_bounds__(1024, 4) void pdhg_persist(
    const float* __restrict__ x,
    const float* __restrict__ lam,
    const float* __restrict__ tau_p,
    const float* __restrict__ sigma_p,
    const float* __restrict__ theta_p,
    float* __restrict__ xbar_g,   // 2 * NSITES (ping-pong)
    float* __restrict__ q0_g,     // 2 * NSITES (ping-pong)
    unsigned* __restrict__ bar,
    float* __restrict__ out)
{
    __shared__ float xb_lds[2][PLANE];
    __shared__ float q1_lds[2][PLANE];
    __shared__ float q2_lds[2][PLANE];

    const int b   = blockIdx.x;        // plane = p*128 + ix
    const int tid = threadIdx.x;       // y*8 + t
    const int pp  = b >> 7;
    const int ix  = b & 127;
    const int idx = b * PLANE + tid;

    const int t = tid & 7;
    const int g_xp = ((pp << 7) + ((ix + 1) & 127)) * PLANE + tid;
    const int g_xm = ((pp << 7) + ((ix + 127) & 127)) * PLANE + tid;
    const int l_yp = (tid + 8) & (PLANE - 1);
    const int l_ym = (tid - 8) & (PLANE - 1);
    const int l_tp = (t == 7) ? tid - 7 : tid + 1;
    const int l_tm = (t == 0) ? tid + 7 : tid - 1;

    const float L = 3.605551275463989f;  // sqrt(13)
    const float s_sig = (1.f / (1.f + __expf(-sigma_p[0]))) / L;
    const float s_tau = (1.f / (1.f + __expf(-tau_p[0]))) / L;
    const float s_th  =  1.f / (1.f + __expf(-theta_p[0]));
    const float inv1s = 1.f / (1.f + s_sig);

    const float xn   = x[idx];
    const float lamc = lam[idx];
    const float lxm  = lam[g_xm];
    const float lym  = lam[b * PLANE + l_ym];
    const float ltm  = lam[b * PLANE + l_tm];

    // register-resident state for all 128 steps
    float x0v = xn, pv = xn, q0v = 0.f, q1v = 0.f, q2v = 0.f, xbv = xn;

    auto step_math = [&](float xbxp, float xbxm, float xbyp, float xbym,
                         float xbtp, float xbtm, float q0xm, float q1ym, float q2tm) {
        const float p_new = (pv + s_sig * (xbv - xn)) * inv1s;
        const float q0n = fmaxf(-lamc, fminf(lamc, q0v + s_sig * (xbxp - xbv)));
        const float q1n = fmaxf(-lamc, fminf(lamc, q1v + s_sig * (xbyp - xbv)));
        const float q2n = fmaxf(-lamc, fminf(lamc, q2v + s_sig * (xbtp - xbv)));
        // backward neighbors' new q (redundant compute -> single phase per step)
        const float q0nm = fmaxf(-lxm, fminf(lxm, q0xm + s_sig * (xbv - xbxm)));
        const float q1nm = fmaxf(-lym, fminf(lym, q1ym + s_sig * (xbv - xbym)));
        const float q2nm = fmaxf(-ltm, fminf(ltm, q2tm + s_sig * (xbv - xbtm)));
        const float div = (q0nm - q0n) + (q1nm - q1n) + (q2nm - q2n);
        const float x1 = x0v - s_tau * (p_new + div);
        const float xb_new = x1 + s_th * (x1 - x0v);
        pv = p_new; q0v = q0n; q1v = q1n; q2v = q2n;
        x0v = x1; xbv = xb_new;
    };

    // ---- step 0: xbar = x, q = 0, plain loads from input ----
    step_math(x[g_xp], x[g_xm],
              x[b * PLANE + l_yp], x[b * PLANE + l_ym],
              x[b * PLANE + l_tp], x[b * PLANE + l_tm],
              0.f, 0.f, 0.f);
    {
        const int w = 0;
        // publish cross-block state first (longest latency), then LDS
        __hip_atomic_store(&xbar_g[w * NSITES + idx], xbv, __ATOMIC_RELAXED, AGENT);
        __hip_atomic_store(&q0_g[w * NSITES + idx],  q0v, __ATOMIC_RELAXED, AGENT);
        xb_lds[w][tid] = xbv; q1_lds[w][tid] = q1v; q2_lds[w][tid] = q2v;
        gridbar(bar, 1u);  // barrier after step 0
    }

    for (int s = 1; s < TSTEPS; ++s) {
        const int r = (s & 1) ^ 1;     // buffer published by step s-1
        const int w = s & 1;

        // cross-block (x +/- 1) via LLC-coherent loads — issue first
        const float xbxp = __hip_atomic_load(&xbar_g[r * NSITES + g_xp], __ATOMIC_RELAXED, AGENT);
        const float xbxm = __hip_atomic_load(&xbar_g[r * NSITES + g_xm], __ATOMIC_RELAXED, AGENT);
        const float q0xm = __hip_atomic_load(&q0_g[r * NSITES + g_xm],  __ATOMIC_RELAXED, AGENT);
        // in-plane neighbors via LDS
        const float xbyp = xb_lds[r][l_yp];
        const float xbym = xb_lds[r][l_ym];
        const float xbtp = xb_lds[r][l_tp];
        const float xbtm = xb_lds[r][l_tm];
        const float q1ym = q1_lds[r][l_ym];
        const float q2tm = q2_lds[r][l_tm];

        step_math(xbxp, xbxm, xbyp, xbym, xbtp, xbtm, q0xm, q1ym, q2tm);

        if (s < TSTEPS - 1) {
            __hip_atomic_store(&xbar_g[w * NSITES + idx], xbv, __ATOMIC_RELAXED, AGENT);
            __hip_atomic_store(&q0_g[w * NSITES + idx],  q0v, __ATOMIC_RELAXED, AGENT);
            xb_lds[w][tid] = xbv; q1_lds[w][tid] = q1v; q2_lds[w][tid] = q2v;
            gridbar(bar, (unsigned)(s + 1));
        }
    }

    out[idx] = x0v;   // x1 after step 127
}

extern "C" void kernel_launch(void* const* d_in, const int* in_sizes, int n_in,
                              void* d_out, int out_size, void* d_ws, size_t ws_size,
                              hipStream_t stream) {
    const float* x   = (const float*)d_in[0];
    const float* lam = (const float*)d_in[1];
    const float* tau = (const float*)d_in[2];
    const float* sig = (const float*)d_in[3];
    const float* th  = (const float*)d_in[4];
    float* out = (float*)d_out;

    float* ws = (float*)d_ws;
    float* xbar_g = ws;                               // 2*NSITES floats
    float* q0_g   = ws + 2 * (size_t)NSITES;          // 2*NSITES floats
    unsigned* bar = (unsigned*)(ws + 4 * (size_t)NSITES);

    // ws is poisoned to 0xAA before every timed call: zero the barrier block
    hipMemsetAsync(bar, 0, 4096, stream);

    void* args[] = {
        (void*)&x, (void*)&lam, (void*)&tau, (void*)&sig, (void*)&th,
        (void*)&xbar_g, (void*)&q0_g, (void*)&bar, (void*)&out
    };
    hipLaunchCooperativeKernel((const void*)pdhg_persist,
                               dim3(NBLK), dim3(PLANE), args, 0, stream);
}